// Round 5
// baseline (115.293 us; speedup 1.0000x reference)
//
#include <hip/hip_runtime.h>
#include <math.h>

#define BB 32
#define TT 2048
#define DD 64
#define PRED 96
#define TP (TT + PRED)      // 2144
#define KTOP 8
#define NCAND 12
#define NSIG (BB * DD)      // 2048
#define MARGIN 2e-4f
#define PI_D 3.14159265358979323846

// LDS bank swizzle for the float2 FFT array: phys = idx ^ ((idx>>5)&31).
__device__ __forceinline__ int physIdx(int idx) { return idx ^ ((idx >> 5) & 31); }

// DIF digit-reversal (radices 8,8,8,4): bin k lives at this LDS position.
__device__ __forceinline__ int posOf(int k) {
    return ((k & 7) << 8) | (((k >> 3) & 7) << 5) | (((k >> 6) & 7) << 2) | (k >> 9);
}

__device__ __forceinline__ float2 cadd(float2 a, float2 b) { return make_float2(a.x + b.x, a.y + b.y); }
__device__ __forceinline__ float2 csub(float2 a, float2 b) { return make_float2(a.x - b.x, a.y - b.y); }
__device__ __forceinline__ float2 cmulni(float2 a) { return make_float2(a.y, -a.x); }   // * -i
__device__ __forceinline__ float2 cmulpi(float2 a) { return make_float2(-a.y, a.x); }   // * +i
__device__ __forceinline__ float2 cw8(float2 a) {   // * exp(-i*pi/4)
    const float s = 0.70710678118654752f;
    return make_float2(s * (a.x + a.y), s * (a.y - a.x));
}
__device__ __forceinline__ float2 cw83(float2 a) {  // * exp(-i*3pi/4)
    const float s = 0.70710678118654752f;
    return make_float2(s * (a.y - a.x), -s * (a.x + a.y));
}
// * exp(-2*pi*i*m/2048) via 1-ulp HW trig (input in revolutions)
__device__ __forceinline__ float2 ctw(float2 a, int m) {
    const float rev = (float)m * (1.0f / 2048.0f);
    const float c = __builtin_amdgcn_cosf(rev);
    const float s = __builtin_amdgcn_sinf(rev);
    return make_float2(a.x * c + a.y * s, a.y * c - a.x * s);
}

// 8-point DFT in registers (DIF core)
__device__ __forceinline__ void radix8(float2* r) {
    float2 E0, E1, E2, E3, O0, O1, O2, O3;
    {
        float2 s0 = cadd(r[0], r[4]), s1 = csub(r[0], r[4]);
        float2 s2 = cadd(r[2], r[6]), s3 = csub(r[2], r[6]);
        E0 = cadd(s0, s2); E2 = csub(s0, s2);
        E1 = cadd(s1, cmulni(s3)); E3 = cadd(s1, cmulpi(s3));
    }
    {
        float2 s0 = cadd(r[1], r[5]), s1 = csub(r[1], r[5]);
        float2 s2 = cadd(r[3], r[7]), s3 = csub(r[3], r[7]);
        O0 = cadd(s0, s2); O2 = csub(s0, s2);
        O1 = cadd(s1, cmulni(s3)); O3 = cadd(s1, cmulpi(s3));
    }
    const float2 w1 = cw8(O1), w2 = cmulni(O2), w3 = cw83(O3);
    r[0] = cadd(E0, O0); r[4] = csub(E0, O0);
    r[1] = cadd(E1, w1); r[5] = csub(E1, w1);
    r[2] = cadd(E2, w2); r[6] = csub(E2, w2);
    r[3] = cadd(E3, w3); r[7] = csub(E3, w3);
}

// ---------------------------------------------------------------------------
// Transpose: x[b, n, d] (float2 over d-pairs) -> xT[(b*32+dp)*2048 + n].
// Both global sides fully coalesced; 64n x 32dp float2 tile via LDS.
// Same XCD swizzle as the FFT kernel so each batch stays in one XCD's L2.
// ---------------------------------------------------------------------------
__global__ __launch_bounds__(256) void transpose_kernel(const float* __restrict__ x,
                                                        float2* __restrict__ xT) {
    __shared__ float2 tile[64][33];                // +1 pad

    const int i     = blockIdx.x;
    const int xcd   = i & 7;
    const int slot  = i >> 3;                      // 0..127
    const int b     = xcd * 4 + (slot >> 5);       // 0..31
    const int ntile = slot & 31;                   // 0..31
    const int n0    = ntile * 64;
    const int t     = threadIdx.x;

    const float2* xv = (const float2*)x;
    // Read: lanes sweep dp (contiguous 256B per 32 lanes).
    const int c = t & 31, r0 = t >> 5;             // c: dp, r0: 0..7
    #pragma unroll
    for (int q = 0; q < 8; ++q) {
        const int n = n0 + r0 + 8 * q;
        tile[r0 + 8 * q][c] = xv[((size_t)b * TT + n) * (DD / 2) + c];
    }
    __syncthreads();

    // Write: lanes sweep n (contiguous 512B per wave).
    const int ln = t & 63, wq = t >> 6;            // ln: n-offset, wq: 0..3
    #pragma unroll
    for (int q = 0; q < 8; ++q) {
        const int dp = wq + 4 * q;                 // 0..31
        xT[((size_t)(b * (DD / 2) + dp)) * TT + n0 + ln] = tile[ln][dp];
    }
}

// ---------------------------------------------------------------------------
// Fused kernel: fp32 radix-8/8/8/4 FFT (2 packed real channels, from the
// transposed layout -> coalesced loads) + one-wave top-12 selection +
// in-block fp64 refine for risk-flagged signals. LDS ~18 KB -> 8 blocks/CU.
// ---------------------------------------------------------------------------
__global__ __launch_bounds__(256) void fft_topk_kernel(const float2* __restrict__ xT,
                                                       int* __restrict__ idxw,
                                                       float* __restrict__ rew,
                                                       float* __restrict__ imw) {
    __shared__ float2 Z[TT];                       // 16 KB, swizzled; reused in refine
    __shared__ int    candS[2][NCAND];
    __shared__ int    flagS[2];
    __shared__ double resR[2][NCAND], resI[2][NCAND], resM[2][NCAND];
    __shared__ double2 wA[32];                     // exp(-i*pi*q/16)
    __shared__ double2 wB[64];                     // exp(-2*pi*i*j/2048)

    const int i    = blockIdx.x;
    const int xcd  = i & 7;
    const int slot = i >> 3;
    const int b    = xcd * 4 + (slot >> 5);
    const int dp   = slot & 31;
    const int t    = threadIdx.x;

    const size_t base = (size_t)(b * (DD / 2) + dp) * TT;
    float2 r[8];
    #pragma unroll
    for (int q = 0; q < 8; ++q) r[q] = xT[base + t + 256 * q];   // coalesced

    // Phase 1: L=2048
    radix8(r);
    #pragma unroll
    for (int p = 1; p < 8; ++p) r[p] = ctw(r[p], (p * t) & (TT - 1));
    #pragma unroll
    for (int p = 0; p < 8; ++p) Z[physIdx(t + (p << 8))] = r[p];
    __syncthreads();

    // Phase 2: L=256
    const int S2 = (t >> 5) << 8, j2 = t & 31;
    #pragma unroll
    for (int p = 0; p < 8; ++p) r[p] = Z[physIdx(S2 + j2 + (p << 5))];
    radix8(r);
    #pragma unroll
    for (int p = 1; p < 8; ++p) r[p] = ctw(r[p], (8 * p * j2) & (TT - 1));
    #pragma unroll
    for (int p = 0; p < 8; ++p) Z[physIdx(S2 + j2 + (p << 5))] = r[p];
    __syncthreads();

    // Phase 3: L=32
    const int S3 = (t >> 2) << 5, j3 = t & 3;
    #pragma unroll
    for (int p = 0; p < 8; ++p) r[p] = Z[physIdx(S3 + j3 + (p << 2))];
    radix8(r);
    #pragma unroll
    for (int p = 1; p < 8; ++p) r[p] = ctw(r[p], (64 * p * j3) & (TT - 1));
    #pragma unroll
    for (int p = 0; p < 8; ++p) Z[physIdx(S3 + j3 + (p << 2))] = r[p];
    __syncthreads();

    // Phase 4: two final DFT4s on consecutive quads
    #pragma unroll
    for (int g = 0; g < 2; ++g) {
        const int b4 = 8 * t + 4 * g;
        const float2 a = Z[physIdx(b4)],     bb = Z[physIdx(b4 + 1)];
        const float2 c = Z[physIdx(b4 + 2)], dd = Z[physIdx(b4 + 3)];
        const float2 s0 = cadd(a, c), s1 = csub(a, c);
        const float2 s2 = cadd(bb, dd), s3 = csub(bb, dd);
        Z[physIdx(b4)]     = cadd(s0, s2);
        Z[physIdx(b4 + 1)] = cadd(s1, cmulni(s3));
        Z[physIdx(b4 + 2)] = csub(s0, s2);
        Z[physIdx(b4 + 3)] = cadd(s1, cmulpi(s3));
    }
    __syncthreads();

    // One wave per signal: magnitudes straight from Z, then top-12 via
    // shuffle-max passes (no barriers). Keys: magbits<<32 | 4095-k.
    const int wv = t >> 6, lane = t & 63;
    if (wv < 2) {
        const int sig = wv;
        unsigned long long kk[16];
        #pragma unroll
        for (int m = 0; m < 16; ++m) {
            const int k = lane + 64 * m;           // 0..1023; k=0 excluded
            unsigned long long key = 0ULL;
            if (k != 0) {
                const float2 z = Z[physIdx(posOf(k))];
                const float2 y = Z[physIdx(posOf(TT - k))];
                float cr, ci;
                if (sig == 0) { cr = 0.5f * (z.x + y.x); ci = 0.5f * (z.y - y.y); }
                else          { cr = 0.5f * (z.y + y.y); ci = 0.5f * (y.x - z.x); }
                const float mg = cr * cr + ci * ci;
                key = ((unsigned long long)__float_as_uint(mg) << 32) | (unsigned)(4095 - k);
            }
            kk[m] = key;
        }
        unsigned long long local = 0;
        #pragma unroll
        for (int m = 0; m < 16; ++m) local = (kk[m] > local) ? kk[m] : local;

        unsigned long long mykey = 0;              // lane r keeps pass-r winner
        for (int pass = 0; pass < NCAND; ++pass) {
            unsigned long long w = local;
            #pragma unroll
            for (int off = 1; off < 64; off <<= 1) {
                const unsigned long long o = __shfl_xor(w, off, 64);
                if (o > w) w = o;
            }
            if (w == local && w != 0ULL) {         // owner invalidates
                #pragma unroll
                for (int m = 0; m < 16; ++m) if (kk[m] == w) kk[m] = 0ULL;
                local = 0;
                #pragma unroll
                for (int m = 0; m < 16; ++m) local = (kk[m] > local) ? kk[m] : local;
            }
            if (lane == pass) mykey = w;
        }

        const unsigned long long k7 = __shfl(mykey, 7, 64);
        const unsigned long long k8 = __shfl(mykey, 8, 64);
        const float m8 = __uint_as_float((unsigned)(k7 >> 32));
        const float m9 = __uint_as_float((unsigned)(k8 >> 32));
        const int flg = (m8 - m9 <= MARGIN * m8) ? 1 : 0;   // wave-uniform
        if (lane == 0) flagS[sig] = flg;

        const int kwin = 4095 - (int)(mykey & 0xFFFFFFFFULL);
        if (lane < NCAND) candS[sig][lane] = kwin;
        if (!flg && lane < KTOP) {
            const float2 z = Z[physIdx(posOf(kwin))];
            const float2 y = Z[physIdx(posOf(TT - kwin))];
            float cr, ci;
            if (sig == 0) { cr = 0.5f * (z.x + y.x); ci = 0.5f * (z.y - y.y); }
            else          { cr = 0.5f * (z.y + y.y); ci = 0.5f * (y.x - z.x); }
            const int s_sig = b * DD + 2 * dp + sig;
            idxw[s_sig * KTOP + lane] = kwin;
            rew[s_sig * KTOP + lane]  = cr * (2.0f / (float)TT);
            imw[s_sig * KTOP + lane]  = ci * (2.0f / (float)TT);
        }
    }
    __syncthreads();

    // ---- In-block fp64 refine (rare path, ~1% of blocks). Z is dead: reuse
    // it to restage the raw signal (coalesced reload from xT).
    if (flagS[0] | flagS[1]) {
        #pragma unroll
        for (int q = 0; q < 8; ++q)
            Z[t + 256 * q] = xT[base + t + 256 * q];
        // fp64 twiddles: tw(m) = wA[m>>6] * wB[m&63] (2-ulp product)
        if (t < 32) {
            const double th = -PI_D * (double)t / 16.0;
            wA[t] = make_double2(cos(th), sin(th));
        } else if (t < 96) {
            const int j = t - 32;
            const double th = -2.0 * PI_D * (double)j / (double)TT;
            wB[j] = make_double2(cos(th), sin(th));
        }
        __syncthreads();

        for (int sig = 0; sig < 2; ++sig) {
            if (!flagS[sig]) continue;
            for (int rr = wv; rr < NCAND; rr += 4) {
                const int k = candS[sig][rr];
                double ar = 0.0, ai = 0.0;
                for (int m = 0; m < TT / 64; ++m) {
                    const int n   = lane + 64 * m;
                    const int ix  = (k * n) & (TT - 1);
                    const double2 a  = wA[ix >> 6];
                    const double2 bw = wB[ix & 63];
                    const double wr = a.x * bw.x - a.y * bw.y;
                    const double wi = a.x * bw.y + a.y * bw.x;
                    const double xn = (sig == 0) ? (double)Z[n].x : (double)Z[n].y;
                    ar = fma(xn, wr, ar);
                    ai = fma(xn, wi, ai);
                }
                #pragma unroll
                for (int off = 32; off; off >>= 1) {
                    ar += __shfl_xor(ar, off, 64);
                    ai += __shfl_xor(ai, off, 64);
                }
                if (lane == 0) {
                    resR[sig][rr] = ar; resI[sig][rr] = ai;
                    resM[sig][rr] = ar * ar + ai * ai;
                }
            }
        }
        __syncthreads();

        if (t < 2 * NCAND) {
            const int sig = t / NCAND, rr = t % NCAND;
            if (flagS[sig]) {
                const double m = resM[sig][rr];
                const int    k = candS[sig][rr];
                int rank = 0;
                for (int r2 = 0; r2 < NCAND; ++r2) {
                    const double m2 = resM[sig][r2];
                    const int    k2 = candS[sig][r2];
                    if (m2 > m || (m2 == m && k2 < k)) ++rank;
                }
                if (rank < KTOP) {
                    const int s_sig = b * DD + 2 * dp + sig;
                    idxw[s_sig * KTOP + rank] = k;
                    rew[s_sig * KTOP + rank]  = (float)(resR[sig][rr] * (2.0 / (double)TT));
                    imw[s_sig * KTOP + rank]  = (float)(resI[sig][rr] * (2.0 / (double)TT));
                }
            }
        }
    }
}

// ---------------------------------------------------------------------------
// Synthesis (verified): d-major lanes, coalesced stores, exact integer angle
// reduction + HW trig.
// ---------------------------------------------------------------------------
__global__ __launch_bounds__(256) void synth_kernel(const int* __restrict__ idxw,
                                                    const float* __restrict__ rew,
                                                    const float* __restrict__ imw,
                                                    float* __restrict__ out) {
    const int NT   = (TP + 127) / 128;   // 17 tiles
    const int b    = blockIdx.x / NT;
    const int tile = blockIdx.x % NT;
    const int tid  = threadIdx.x;
    const int d    = tid & 63;
    const int tq   = tid >> 6;
    const int s    = b * DD + d;

    int   kk[KTOP];
    float rr[KTOP], ii[KTOP];
    int   jj[KTOP];
    #pragma unroll
    for (int p = 0; p < KTOP; ++p) {
        kk[p] = idxw[s * KTOP + p];
        rr[p] = rew[s * KTOP + p];
        ii[p] = imw[s * KTOP + p];
    }
    const int t0 = tile * 128 + tq * 32;
    #pragma unroll
    for (int p = 0; p < KTOP; ++p) jj[p] = (kk[p] * t0) & (TT - 1);

    const float invT = 1.0f / (float)TT;
    for (int i = 0; i < 32; ++i) {
        const int t = t0 + i;
        if (t < TP) {
            float acc = 0.0f;
            #pragma unroll
            for (int p = 0; p < KTOP; ++p) {
                const float rev = (float)jj[p] * invT;
                const float c  = __builtin_amdgcn_cosf(rev);
                const float sn = __builtin_amdgcn_sinf(rev);
                acc += rr[p] * c - ii[p] * sn;
            }
            out[((size_t)b * TP + t) * DD + d] = acc;
        }
        #pragma unroll
        for (int p = 0; p < KTOP; ++p) jj[p] = (jj[p] + kk[p]) & (TT - 1);
    }
}

extern "C" void kernel_launch(void* const* d_in, const int* in_sizes, int n_in,
                              void* d_out, int out_size, void* d_ws, size_t ws_size,
                              hipStream_t stream) {
    const float* x = (const float*)d_in[0];
    float* out = (float*)d_out;

    // ws: xT float2[32*32*2048] (16 MB) | idxw | rew | imw
    char* p = (char*)d_ws;
    float2* xT = (float2*)p;   p += (size_t)BB * (DD / 2) * TT * sizeof(float2);
    int*   idxw = (int*)p;     p += (size_t)NSIG * KTOP * sizeof(int);
    float* rew  = (float*)p;   p += (size_t)NSIG * KTOP * sizeof(float);
    float* imw  = (float*)p;

    transpose_kernel<<<NSIG / 2, 256, 0, stream>>>(x, xT);
    fft_topk_kernel<<<NSIG / 2, 256, 0, stream>>>(xT, idxw, rew, imw);

    const int NT = (TP + 127) / 128;
    synth_kernel<<<BB * NT, 256, 0, stream>>>(idxw, rew, imw, out);
}

// Round 6
// 112.962 us; speedup vs baseline: 1.0206x; 1.0206x over previous
//
#include <hip/hip_runtime.h>
#include <math.h>

#define BB 32
#define TT 2048
#define DD 64
#define PRED 96
#define TP (TT + PRED)      // 2144
#define KTOP 8
#define NCAND 16
#define NSIG (BB * DD)      // 2048
#define MARGIN 8e-4f
#define PI_D 3.14159265358979323846

// LDS bank swizzle for the float2 FFT array: phys = idx ^ ((idx>>5)&31).
__device__ __forceinline__ int physIdx(int idx) { return idx ^ ((idx >> 5) & 31); }

// DIF digit-reversal (radices 8,8,8,4): bin k lives at this LDS position.
__device__ __forceinline__ int posOf(int k) {
    return ((k & 7) << 8) | (((k >> 3) & 7) << 5) | (((k >> 6) & 7) << 2) | (k >> 9);
}

__device__ __forceinline__ float2 cadd(float2 a, float2 b) { return make_float2(a.x + b.x, a.y + b.y); }
__device__ __forceinline__ float2 csub(float2 a, float2 b) { return make_float2(a.x - b.x, a.y - b.y); }
__device__ __forceinline__ float2 cmulni(float2 a) { return make_float2(a.y, -a.x); }   // * -i
__device__ __forceinline__ float2 cmulpi(float2 a) { return make_float2(-a.y, a.x); }   // * +i
__device__ __forceinline__ float2 cw8(float2 a) {   // * exp(-i*pi/4)
    const float s = 0.70710678118654752f;
    return make_float2(s * (a.x + a.y), s * (a.y - a.x));
}
__device__ __forceinline__ float2 cw83(float2 a) {  // * exp(-i*3pi/4)
    const float s = 0.70710678118654752f;
    return make_float2(s * (a.y - a.x), -s * (a.x + a.y));
}
// * exp(-2*pi*i*m/2048) via 1-ulp HW trig (input in revolutions)
__device__ __forceinline__ float2 ctw(float2 a, int m) {
    const float rev = (float)m * (1.0f / 2048.0f);
    const float c = __builtin_amdgcn_cosf(rev);
    const float s = __builtin_amdgcn_sinf(rev);
    return make_float2(a.x * c + a.y * s, a.y * c - a.x * s);
}

// 8-point DFT in registers (DIF core)
__device__ __forceinline__ void radix8(float2* r) {
    float2 E0, E1, E2, E3, O0, O1, O2, O3;
    {
        float2 s0 = cadd(r[0], r[4]), s1 = csub(r[0], r[4]);
        float2 s2 = cadd(r[2], r[6]), s3 = csub(r[2], r[6]);
        E0 = cadd(s0, s2); E2 = csub(s0, s2);
        E1 = cadd(s1, cmulni(s3)); E3 = cadd(s1, cmulpi(s3));
    }
    {
        float2 s0 = cadd(r[1], r[5]), s1 = csub(r[1], r[5]);
        float2 s2 = cadd(r[3], r[7]), s3 = csub(r[3], r[7]);
        O0 = cadd(s0, s2); O2 = csub(s0, s2);
        O1 = cadd(s1, cmulni(s3)); O3 = cadd(s1, cmulpi(s3));
    }
    const float2 w1 = cw8(O1), w2 = cmulni(O2), w3 = cw83(O3);
    r[0] = cadd(E0, O0); r[4] = csub(E0, O0);
    r[1] = cadd(E1, w1); r[5] = csub(E1, w1);
    r[2] = cadd(E2, w2); r[6] = csub(E2, w2);
    r[3] = cadd(E3, w3); r[7] = csub(E3, w3);
}

// ---------------------------------------------------------------------------
// Fused kernel: fp32 radix-8/8/8/4 FFT (2 packed real channels) + per-wave
// bitonic top-16 selection (pipelined shuffles, no serial argmax chains) +
// in-block fp64 refine for margin-flagged signals.
// ---------------------------------------------------------------------------
__global__ __launch_bounds__(256) void fft_topk_kernel(const float* __restrict__ x,
                                                       int* __restrict__ idxw,
                                                       float* __restrict__ rew,
                                                       float* __restrict__ imw) {
    __shared__ float2 Z[TT];                       // 16 KB, swizzled; reused in refine
    __shared__ int    candS[2][NCAND];
    __shared__ int    flagS[2];
    __shared__ double resR[2][NCAND], resI[2][NCAND], resM[2][NCAND];
    __shared__ double2 wA[32];                     // exp(-i*pi*q/16)
    __shared__ double2 wB[64];                     // exp(-2*pi*i*j/2048)

    // XCD swizzle: all 32 dp-blocks of one batch b on one XCD (L2 reuse).
    const int i    = blockIdx.x;
    const int xcd  = i & 7;
    const int slot = i >> 3;
    const int b    = xcd * 4 + (slot >> 5);
    const int dp   = slot & 31;
    const int t    = threadIdx.x;

    const float2* xv = (const float2*)x;
    const size_t base = (size_t)b * TT * (DD / 2) + dp;
    float2 r[8];
    #pragma unroll
    for (int q = 0; q < 8; ++q) r[q] = xv[base + (size_t)(t + 256 * q) * (DD / 2)];

    // Phase 1: L=2048
    radix8(r);
    #pragma unroll
    for (int p = 1; p < 8; ++p) r[p] = ctw(r[p], (p * t) & (TT - 1));
    #pragma unroll
    for (int p = 0; p < 8; ++p) Z[physIdx(t + (p << 8))] = r[p];
    __syncthreads();

    // Phase 2: L=256
    const int S2 = (t >> 5) << 8, j2 = t & 31;
    #pragma unroll
    for (int p = 0; p < 8; ++p) r[p] = Z[physIdx(S2 + j2 + (p << 5))];
    radix8(r);
    #pragma unroll
    for (int p = 1; p < 8; ++p) r[p] = ctw(r[p], (8 * p * j2) & (TT - 1));
    #pragma unroll
    for (int p = 0; p < 8; ++p) Z[physIdx(S2 + j2 + (p << 5))] = r[p];
    __syncthreads();

    // Phase 3: L=32
    const int S3 = (t >> 2) << 5, j3 = t & 3;
    #pragma unroll
    for (int p = 0; p < 8; ++p) r[p] = Z[physIdx(S3 + j3 + (p << 2))];
    radix8(r);
    #pragma unroll
    for (int p = 1; p < 8; ++p) r[p] = ctw(r[p], (64 * p * j3) & (TT - 1));
    #pragma unroll
    for (int p = 0; p < 8; ++p) Z[physIdx(S3 + j3 + (p << 2))] = r[p];
    __syncthreads();

    // Phase 4: two final DFT4s on consecutive quads
    #pragma unroll
    for (int g = 0; g < 2; ++g) {
        const int b4 = 8 * t + 4 * g;
        const float2 a = Z[physIdx(b4)],     bb = Z[physIdx(b4 + 1)];
        const float2 c = Z[physIdx(b4 + 2)], dd = Z[physIdx(b4 + 3)];
        const float2 s0 = cadd(a, c), s1 = csub(a, c);
        const float2 s2 = cadd(bb, dd), s3 = csub(bb, dd);
        Z[physIdx(b4)]     = cadd(s0, s2);
        Z[physIdx(b4 + 1)] = cadd(s1, cmulni(s3));
        Z[physIdx(b4 + 2)] = csub(s0, s2);
        Z[physIdx(b4 + 3)] = cadd(s1, cmulpi(s3));
    }
    __syncthreads();

    // ---- Selection: wave 0 -> sig0 (.x path), wave 1 -> sig1 (.y path). ----
    // u32 keys: (mag2 bits & ~0x7FF) | (2047-k). 12 mantissa bits kept; any
    // ordering ambiguity from the 2.44e-4 truncation quantum is covered by
    // MARGIN -> fp64 refine. Larger key = (bigger mag, then smaller k).
    const int wv = t >> 6, lane = t & 63;
    if (wv < 2) {
        const int sig = wv;
        unsigned A[16];
        #pragma unroll
        for (int m = 0; m < 16; ++m) {
            const int k = lane + (m << 6);         // 0..1023
            unsigned key = 0u;
            if (k != 0) {
                const float2 z = Z[physIdx(posOf(k))];
                const float2 y = Z[physIdx(posOf(TT - k))];
                float cr, ci;
                if (sig == 0) { cr = 0.5f * (z.x + y.x); ci = 0.5f * (z.y - y.y); }
                else          { cr = 0.5f * (z.y + y.y); ci = 0.5f * (y.x - z.x); }
                const float mg = cr * cr + ci * ci;
                key = (__float_as_uint(mg) & 0xFFFFF800u) | (unsigned)(2047 - k);
            }
            A[m] = key;
        }

        // In-register bitonic sort-16, descending (pure VALU).
        #pragma unroll
        for (int sz = 2; sz <= 16; sz <<= 1) {
            #pragma unroll
            for (int d = sz >> 1; d > 0; d >>= 1) {
                #pragma unroll
                for (int i2 = 0; i2 < 16; ++i2) {
                    const int j2i = i2 ^ d;
                    if (j2i > i2) {
                        const bool desc = ((i2 & sz) == 0);
                        const unsigned a = A[i2], b2 = A[j2i];
                        const unsigned mx = a > b2 ? a : b2;
                        const unsigned mn = a > b2 ? b2 : a;
                        A[i2]  = desc ? mx : mn;
                        A[j2i] = desc ? mn : mx;
                    }
                }
            }
        }

        // 6 XOR-merge stages: pipelined shuffles + max-trick + half-clean.
        #pragma unroll
        for (int off = 1; off < 64; off <<= 1) {
            unsigned Bv[16];
            #pragma unroll
            for (int i2 = 0; i2 < 16; ++i2)
                Bv[i2] = (unsigned)__shfl_xor((int)A[i2], off, 64);
            #pragma unroll
            for (int i2 = 0; i2 < 16; ++i2) {
                const unsigned o = Bv[15 - i2];
                A[i2] = A[i2] > o ? A[i2] : o;     // top-16 multiset, bitonic
            }
            #pragma unroll
            for (int d = 8; d > 0; d >>= 1) {
                #pragma unroll
                for (int i2 = 0; i2 < 16; ++i2) {
                    if ((i2 & d) == 0) {
                        const int j2i = i2 + d;
                        const unsigned a = A[i2], b2 = A[j2i];
                        A[i2]  = a > b2 ? a : b2;
                        A[j2i] = a > b2 ? b2 : a;
                    }
                }
            }
        }
        // Every lane now holds the global top-16, descending.

        const float mf8 = __uint_as_float(A[7] & 0xFFFFF800u);
        const float mf9 = __uint_as_float(A[8] & 0xFFFFF800u);
        const int flg = (mf8 - mf9 <= MARGIN * mf8) ? 1 : 0;   // wave-uniform
        if (lane == 0) flagS[sig] = flg;

        // lane r takes element r (unrolled select; avoids reg indexing).
        unsigned myk = 0u;
        #pragma unroll
        for (int i2 = 0; i2 < 16; ++i2) myk = (lane == i2) ? A[i2] : myk;
        const int kwin = 2047 - (int)(myk & 0x7FFu);

        if (lane < NCAND) candS[sig][lane] = kwin;
        if (!flg && lane < KTOP) {
            const float2 z = Z[physIdx(posOf(kwin))];
            const float2 y = Z[physIdx(posOf(TT - kwin))];
            float cr, ci;
            if (sig == 0) { cr = 0.5f * (z.x + y.x); ci = 0.5f * (z.y - y.y); }
            else          { cr = 0.5f * (z.y + y.y); ci = 0.5f * (y.x - z.x); }
            const int s_sig = b * DD + 2 * dp + sig;
            idxw[s_sig * KTOP + lane] = kwin;
            rew[s_sig * KTOP + lane]  = cr * (2.0f / (float)TT);
            imw[s_sig * KTOP + lane]  = ci * (2.0f / (float)TT);
        }
    }
    __syncthreads();

    // ---- In-block fp64 refine (rare path). Z is dead: restage raw signal.
    if (flagS[0] | flagS[1]) {
        #pragma unroll
        for (int q = 0; q < 8; ++q)
            Z[t + 256 * q] = xv[base + (size_t)(t + 256 * q) * (DD / 2)];
        // fp64 twiddles: tw(m) = wA[m>>6] * wB[m&63] (2-ulp product)
        if (t < 32) {
            const double th = -PI_D * (double)t / 16.0;
            wA[t] = make_double2(cos(th), sin(th));
        } else if (t < 96) {
            const int j = t - 32;
            const double th = -2.0 * PI_D * (double)j / (double)TT;
            wB[j] = make_double2(cos(th), sin(th));
        }
        __syncthreads();

        for (int sig = 0; sig < 2; ++sig) {
            if (!flagS[sig]) continue;
            for (int rr = wv; rr < NCAND; rr += 4) {
                const int k = candS[sig][rr];
                double ar = 0.0, ai = 0.0;
                for (int m = 0; m < TT / 64; ++m) {
                    const int n   = lane + 64 * m;
                    const int ix  = (k * n) & (TT - 1);
                    const double2 a  = wA[ix >> 6];
                    const double2 bw = wB[ix & 63];
                    const double wr = a.x * bw.x - a.y * bw.y;
                    const double wi = a.x * bw.y + a.y * bw.x;
                    const double xn = (sig == 0) ? (double)Z[n].x : (double)Z[n].y;
                    ar = fma(xn, wr, ar);
                    ai = fma(xn, wi, ai);
                }
                #pragma unroll
                for (int off = 32; off; off >>= 1) {
                    ar += __shfl_xor(ar, off, 64);
                    ai += __shfl_xor(ai, off, 64);
                }
                if (lane == 0) {
                    resR[sig][rr] = ar; resI[sig][rr] = ai;
                    resM[sig][rr] = ar * ar + ai * ai;
                }
            }
        }
        __syncthreads();

        if (t < 2 * NCAND) {
            const int sig = t / NCAND, rr = t % NCAND;
            if (flagS[sig]) {
                const double m = resM[sig][rr];
                const int    k = candS[sig][rr];
                int rank = 0;
                for (int r2 = 0; r2 < NCAND; ++r2) {
                    const double m2 = resM[sig][r2];
                    const int    k2 = candS[sig][r2];
                    if (m2 > m || (m2 == m && k2 < k)) ++rank;
                }
                if (rank < KTOP) {
                    const int s_sig = b * DD + 2 * dp + sig;
                    idxw[s_sig * KTOP + rank] = k;
                    rew[s_sig * KTOP + rank]  = (float)(resR[sig][rr] * (2.0 / (double)TT));
                    imw[s_sig * KTOP + rank]  = (float)(resI[sig][rr] * (2.0 / (double)TT));
                }
            }
        }
    }
}

// ---------------------------------------------------------------------------
// Synthesis (verified): d-major lanes, coalesced stores, exact integer angle
// reduction + HW trig.
// ---------------------------------------------------------------------------
__global__ __launch_bounds__(256) void synth_kernel(const int* __restrict__ idxw,
                                                    const float* __restrict__ rew,
                                                    const float* __restrict__ imw,
                                                    float* __restrict__ out) {
    const int NT   = (TP + 127) / 128;   // 17 tiles
    const int b    = blockIdx.x / NT;
    const int tile = blockIdx.x % NT;
    const int tid  = threadIdx.x;
    const int d    = tid & 63;
    const int tq   = tid >> 6;
    const int s    = b * DD + d;

    int   kk[KTOP];
    float rr[KTOP], ii[KTOP];
    int   jj[KTOP];
    #pragma unroll
    for (int p = 0; p < KTOP; ++p) {
        kk[p] = idxw[s * KTOP + p];
        rr[p] = rew[s * KTOP + p];
        ii[p] = imw[s * KTOP + p];
    }
    const int t0 = tile * 128 + tq * 32;
    #pragma unroll
    for (int p = 0; p < KTOP; ++p) jj[p] = (kk[p] * t0) & (TT - 1);

    const float invT = 1.0f / (float)TT;
    for (int i = 0; i < 32; ++i) {
        const int t = t0 + i;
        if (t < TP) {
            float acc = 0.0f;
            #pragma unroll
            for (int p = 0; p < KTOP; ++p) {
                const float rev = (float)jj[p] * invT;
                const float c  = __builtin_amdgcn_cosf(rev);
                const float sn = __builtin_amdgcn_sinf(rev);
                acc += rr[p] * c - ii[p] * sn;
            }
            out[((size_t)b * TP + t) * DD + d] = acc;
        }
        #pragma unroll
        for (int p = 0; p < KTOP; ++p) jj[p] = (jj[p] + kk[p]) & (TT - 1);
    }
}

extern "C" void kernel_launch(void* const* d_in, const int* in_sizes, int n_in,
                              void* d_out, int out_size, void* d_ws, size_t ws_size,
                              hipStream_t stream) {
    const float* x = (const float*)d_in[0];
    float* out = (float*)d_out;

    // ws: idxw | rew | imw
    char* p = (char*)d_ws;
    int*   idxw = (int*)p;     p += (size_t)NSIG * KTOP * sizeof(int);
    float* rew  = (float*)p;   p += (size_t)NSIG * KTOP * sizeof(float);
    float* imw  = (float*)p;

    fft_topk_kernel<<<NSIG / 2, 256, 0, stream>>>(x, idxw, rew, imw);

    const int NT = (TP + 127) / 128;
    synth_kernel<<<BB * NT, 256, 0, stream>>>(idxw, rew, imw, out);
}